// Round 2
// baseline (13082.721 us; speedup 1.0000x reference)
//
#include <hip/hip_runtime.h>
#include <math.h>

#define NB 32      // batch
#define NF 512     // feature_size (source positions)
#define ND 256     // d_model
#define NT 32      // decode steps
#define RPB 32     // rows (f positions) per attention block
#define NTILE (NF / RPB)   // 16 f-tiles

__device__ __forceinline__ float sigmoidf_(float x) { return 1.0f / (1.0f + __expf(-x)); }

// ---------------- positional encoding q[F][D] ----------------
__global__ void pe_kernel(float* __restrict__ q) {
    int p = blockIdx.x;      // 0..511
    int d = threadIdx.x;     // 0..255
    float i2 = (float)((d >> 1) << 1);                 // 2i
    // ang = p / 10000^(2i/D) = p * exp(-ln(10000) * 2i/D)
    float rate = expf(-9.210340371976184f * (i2 / (float)ND));
    float ang = (float)p * rate;
    q[p * ND + d] = (d & 1) ? cosf(ang) : sinf(ang);
}

// ---------------- dec = emb[ids]  [B*T][D] ----------------
__global__ void gather_kernel(const int* __restrict__ ids, const float* __restrict__ emb,
                              float* __restrict__ dec) {
    int bt = blockIdx.x;
    int d = threadIdx.x;
    dec[(size_t)bt * ND + d] = emb[(size_t)ids[bt] * ND + d];
}

// ---------------- qwq[p][o] = dot(q[p,:], w_q[o,:]) ----------------
__global__ void qwq_kernel(const float* __restrict__ q, const float* __restrict__ w_q,
                           float* __restrict__ qwq) {
    int p = blockIdx.x;
    int o = threadIdx.x;
    __shared__ float qs[ND];
    qs[o] = q[(size_t)p * ND + o];
    __syncthreads();
    const float4* wr = (const float4*)(w_q + (size_t)o * ND);
    float acc = 0.f;
    for (int k4 = 0; k4 < ND / 4; ++k4) {
        float4 w = wr[k4];
        int k = 4 * k4;
        acc += qs[k] * w.x + qs[k + 1] * w.y + qs[k + 2] * w.z + qs[k + 3] * w.w;
    }
    qwq[(size_t)p * ND + o] = acc;
}

// ---------------- base[b,f,o] = dot(f[b,f,:], w_f[o,:]) + qwq[f,o] ----------------
__global__ void base_kernel(const float* __restrict__ fin, const float* __restrict__ w_f,
                            const float* __restrict__ qwq, float* __restrict__ base) {
    int b = blockIdx.x / NTILE;
    int f0 = (blockIdx.x % NTILE) * RPB;
    int o = threadIdx.x;
    __shared__ float fs[RPB][ND];
    #pragma unroll
    for (int r = 0; r < RPB; ++r)
        fs[r][o] = fin[((size_t)(b * NF + f0 + r)) * ND + o];
    __syncthreads();
    float acc[RPB];
    #pragma unroll
    for (int r = 0; r < RPB; ++r) acc[r] = 0.f;
    const float4* wr = (const float4*)(w_f + (size_t)o * ND);
    for (int k4 = 0; k4 < ND / 4; ++k4) {
        float4 w = wr[k4];
        int k = 4 * k4;
        #pragma unroll
        for (int r = 0; r < RPB; ++r)
            acc[r] += fs[r][k] * w.x + fs[r][k + 1] * w.y + fs[r][k + 2] * w.z + fs[r][k + 3] * w.w;
    }
    #pragma unroll
    for (int r = 0; r < RPB; ++r)
        base[((size_t)(b * NF + f0 + r)) * ND + o] = acc[r] + qwq[(size_t)(f0 + r) * ND + o];
}

// ---------------- per-step LSTM + pred(t-1) + hwh ----------------
// call with t in [0, NT]; t==NT does only the final pred.
__global__ void lstm_step_kernel(int t,
                                 const float* __restrict__ dec,
                                 const float* __restrict__ cpart, const float* __restrict__ cppart,
                                 float* __restrict__ h, float* __restrict__ cell,
                                 float* __restrict__ hwh,
                                 const float* __restrict__ w_ih, const float* __restrict__ w_hh,
                                 const float* __restrict__ w_h, const float* __restrict__ w_g,
                                 float* __restrict__ out) {
    int b = blockIdx.x;
    int tid = threadIdx.x;
    __shared__ float xin[2 * ND];
    __shared__ float hprev[ND];
    __shared__ float cvec[ND];
    __shared__ float hnew[ND];

    float csum = 0.f, cpsum = 0.f;
    if (t > 0) {
        for (int tile = 0; tile < NTILE; ++tile) {
            csum  += cpart [((size_t)tile * NB + b) * ND + tid];
            cpsum += cppart[((size_t)tile * NB + b) * ND + tid];
        }
    }
    hprev[tid] = h[(size_t)b * ND + tid];
    cvec[tid] = csum;
    xin[tid] = (t < NT) ? dec[((size_t)b * NT + t) * ND + tid] : 0.0f;
    xin[ND + tid] = cpsum;
    __syncthreads();

    // pred for step t-1: concat([c, h_prev]) @ w_g.T
    if (t > 0) {
        const float4* wg = (const float4*)(w_g + (size_t)tid * (2 * ND));
        float p = 0.f;
        for (int k4 = 0; k4 < ND / 4; ++k4) {
            float4 w = wg[k4]; int k = 4 * k4;
            p += cvec[k] * w.x + cvec[k + 1] * w.y + cvec[k + 2] * w.z + cvec[k + 3] * w.w;
        }
        for (int k4 = ND / 4; k4 < 2 * ND / 4; ++k4) {
            float4 w = wg[k4]; int k = 4 * k4 - ND;
            p += hprev[k] * w.x + hprev[k + 1] * w.y + hprev[k + 2] * w.z + hprev[k + 3] * w.w;
        }
        out[((size_t)b * NT + (t - 1)) * ND + tid] = p;
    }
    if (t == NT) return;

    // gates: j = jj*ND + tid, torch order i,f,g,o
    float g[4];
    #pragma unroll
    for (int jj = 0; jj < 4; ++jj) {
        const float4* wi = (const float4*)(w_ih + (size_t)(jj * ND + tid) * (2 * ND));
        const float4* wh = (const float4*)(w_hh + (size_t)(jj * ND + tid) * ND);
        float a = 0.f;
        for (int k4 = 0; k4 < 2 * ND / 4; ++k4) {
            float4 w = wi[k4]; int k = 4 * k4;
            a += xin[k] * w.x + xin[k + 1] * w.y + xin[k + 2] * w.z + xin[k + 3] * w.w;
        }
        for (int k4 = 0; k4 < ND / 4; ++k4) {
            float4 w = wh[k4]; int k = 4 * k4;
            a += hprev[k] * w.x + hprev[k + 1] * w.y + hprev[k + 2] * w.z + hprev[k + 3] * w.w;
        }
        g[jj] = a;
    }
    float cold = cell[(size_t)b * ND + tid];
    float gi = sigmoidf_(g[0]), gf = sigmoidf_(g[1]);
    float gg = tanhf(g[2]), go = sigmoidf_(g[3]);
    float cnew = gf * cold + gi * gg;
    float hval = go * tanhf(cnew);
    cell[(size_t)b * ND + tid] = cnew;
    h[(size_t)b * ND + tid] = hval;
    hnew[tid] = hval;
    __syncthreads();

    // hwh = h_new @ w_h.T
    const float4* whr = (const float4*)(w_h + (size_t)tid * ND);
    float a = 0.f;
    for (int k4 = 0; k4 < ND / 4; ++k4) {
        float4 w = whr[k4]; int k = 4 * k4;
        a += hnew[k] * w.x + hnew[k + 1] * w.y + hnew[k + 2] * w.z + hnew[k + 3] * w.w;
    }
    hwh[(size_t)b * ND + tid] = a;
}

// ---------------- fused attention step ----------------
// per (b, f-tile): t_in = tanh(hwh + base + sws); e = t_in @ w_e.T;
// alpha = softmax_o(e); partials for c/cp; sws += alpha @ w_s.T
__global__ void attn_step_kernel(const float* __restrict__ base, float* __restrict__ sws,
                                 const float* __restrict__ fin, const float* __restrict__ q,
                                 const float* __restrict__ hwh,
                                 const float* __restrict__ w_e, const float* __restrict__ w_s,
                                 float* __restrict__ cpart, float* __restrict__ cppart) {
    int b = blockIdx.x / NTILE;
    int tile = blockIdx.x % NTILE;
    int f0 = tile * RPB;
    int o = threadIdx.x;

    __shared__ float hwh_s[ND];
    __shared__ float tin[RPB][ND];
    hwh_s[o] = hwh[(size_t)b * ND + o];
    // no sync needed: tin[r][o] below only uses hwh_s[o] written by this thread

    float sval[RPB];
    #pragma unroll
    for (int r = 0; r < RPB; ++r) {
        size_t idx = ((size_t)(b * NF + f0 + r)) * ND + o;
        float sv = sws[idx];
        sval[r] = sv;
        tin[r][o] = tanhf(hwh_s[o] + base[idx] + sv);
    }
    __syncthreads();

    // e-GEMM: e[r][o] = dot(tin[r,:], w_e[o,:])
    float acc[RPB];
    #pragma unroll
    for (int r = 0; r < RPB; ++r) acc[r] = 0.f;
    {
        const float4* wr = (const float4*)(w_e + (size_t)o * ND);
        for (int k4 = 0; k4 < ND / 4; ++k4) {
            float4 w = wr[k4]; int k = 4 * k4;
            #pragma unroll
            for (int r = 0; r < RPB; ++r)
                acc[r] += tin[r][k] * w.x + tin[r][k + 1] * w.y + tin[r][k + 2] * w.z + tin[r][k + 3] * w.w;
        }
    }
    __syncthreads();          // everyone done reading tin
    #pragma unroll
    for (int r = 0; r < RPB; ++r) tin[r][o] = acc[r];   // tin now holds e
    __syncthreads();

    // softmax over o per row; rows split across the 4 waves
    int lane = o & 63, wv = o >> 6;
    for (int r = wv; r < RPB; r += 4) {
        float m = -1e30f;
        #pragma unroll
        for (int kk = lane; kk < ND; kk += 64) m = fmaxf(m, tin[r][kk]);
        #pragma unroll
        for (int off = 32; off >= 1; off >>= 1) m = fmaxf(m, __shfl_xor(m, off));
        float ssum = 0.f;
        #pragma unroll
        for (int kk = lane; kk < ND; kk += 64) {
            float ev = __expf(tin[r][kk] - m);
            tin[r][kk] = ev;
            ssum += ev;
        }
        #pragma unroll
        for (int off = 32; off >= 1; off >>= 1) ssum += __shfl_xor(ssum, off);
        float inv = 1.0f / ssum;
        #pragma unroll
        for (int kk = lane; kk < ND; kk += 64) tin[r][kk] *= inv;
    }
    __syncthreads();          // tin now holds alpha

    // c/cp partial sums over this f-tile (deterministic, no atomics)
    float pc = 0.f, pcp = 0.f;
    #pragma unroll
    for (int r = 0; r < RPB; ++r) {
        float a = tin[r][o];
        size_t idx = ((size_t)(b * NF + f0 + r)) * ND + o;
        float fv = fin[idx];
        float qv = q[(size_t)(f0 + r) * ND + o];
        pc += a * fv;
        pcp += a * (fv + qv);
    }
    cpart [((size_t)tile * NB + b) * ND + o] = pc;
    cppart[((size_t)tile * NB + b) * ND + o] = pcp;

    // sws += alpha @ w_s.T
    float acc2[RPB];
    #pragma unroll
    for (int r = 0; r < RPB; ++r) acc2[r] = 0.f;
    {
        const float4* wr = (const float4*)(w_s + (size_t)o * ND);
        for (int k4 = 0; k4 < ND / 4; ++k4) {
            float4 w = wr[k4]; int k = 4 * k4;
            #pragma unroll
            for (int r = 0; r < RPB; ++r)
                acc2[r] += tin[r][k] * w.x + tin[r][k + 1] * w.y + tin[r][k + 2] * w.z + tin[r][k + 3] * w.w;
        }
    }
    #pragma unroll
    for (int r = 0; r < RPB; ++r) {
        size_t idx = ((size_t)(b * NF + f0 + r)) * ND + o;
        sws[idx] = sval[r] + acc2[r];
    }
}

extern "C" void kernel_launch(void* const* d_in, const int* in_sizes, int n_in,
                              void* d_out, int out_size, void* d_ws, size_t ws_size,
                              hipStream_t stream) {
    const float* fin  = (const float*)d_in[0];
    const int*   ids  = (const int*)  d_in[1];
    const float* emb  = (const float*)d_in[2];
    const float* w_e  = (const float*)d_in[3];
    const float* w_h  = (const float*)d_in[4];
    const float* w_f  = (const float*)d_in[5];
    const float* w_q  = (const float*)d_in[6];
    const float* w_s  = (const float*)d_in[7];
    const float* w_g  = (const float*)d_in[8];
    const float* w_ih = (const float*)d_in[9];
    const float* w_hh = (const float*)d_in[10];
    float* out = (float*)d_out;
    float* ws  = (float*)d_ws;

    size_t off = 0;
    float* q      = ws + off; off += (size_t)NF * ND;        // 131072
    float* qwq    = ws + off; off += (size_t)NF * ND;        // 131072
    float* dec    = ws + off; off += (size_t)NB * NT * ND;   // 262144
    float* base   = ws + off; off += (size_t)NB * NF * ND;   // 4194304
    float* sws    = ws + off; off += (size_t)NB * NF * ND;   // 4194304
    float* h      = ws + off; off += (size_t)NB * ND;
    float* cell   = ws + off; off += (size_t)NB * ND;
    float* hwh    = ws + off; off += (size_t)NB * ND;
    float* cpart  = ws + off; off += (size_t)NTILE * NB * ND;
    float* cppart = ws + off; off += (size_t)NTILE * NB * ND;

    hipMemsetAsync(sws, 0, sizeof(float) * (size_t)NB * NF * ND, stream);
    hipMemsetAsync(h, 0, sizeof(float) * NB * ND, stream);
    hipMemsetAsync(cell, 0, sizeof(float) * NB * ND, stream);

    pe_kernel<<<NF, ND, 0, stream>>>(q);
    gather_kernel<<<NB * NT, ND, 0, stream>>>(ids, emb, dec);
    qwq_kernel<<<NF, ND, 0, stream>>>(q, w_q, qwq);
    base_kernel<<<NB * NTILE, ND, 0, stream>>>(fin, w_f, qwq, base);

    for (int t = 0; t < NT; ++t) {
        lstm_step_kernel<<<NB, ND, 0, stream>>>(t, dec, cpart, cppart, h, cell, hwh,
                                                w_ih, w_hh, w_h, w_g, out);
        attn_step_kernel<<<NB * NTILE, ND, 0, stream>>>(base, sws, fin, q, hwh,
                                                        w_e, w_s, cpart, cppart);
    }
    // final pred for t = NT-1
    lstm_step_kernel<<<NB, ND, 0, stream>>>(NT, dec, cpart, cppart, h, cell, hwh,
                                            w_ih, w_hh, w_h, w_g, out);
}

// Round 5
// 6182.355 us; speedup vs baseline: 2.1161x; 2.1161x over previous
//
#include <hip/hip_runtime.h>
#include <math.h>

#define NB 32      // batch
#define NF 512     // feature_size (source positions)
#define ND 256     // d_model
#define NT 32      // decode steps
#define RPB 32     // rows (f positions) per attention block
#define NTILE (NF / RPB)   // 16 f-tiles

__device__ __forceinline__ float sigmoidf_(float x) { return 1.0f / (1.0f + __expf(-x)); }

// ---------------- positional encoding q[F][D] ----------------
__global__ void pe_kernel(float* __restrict__ q) {
    int p = blockIdx.x;      // 0..511
    int d = threadIdx.x;     // 0..255
    float i2 = (float)((d >> 1) << 1);                 // 2i
    float rate = expf(-9.210340371976184f * (i2 / (float)ND));
    float ang = (float)p * rate;
    q[p * ND + d] = (d & 1) ? cosf(ang) : sinf(ang);
}

// ---------------- dec = emb[ids]  [B*T][D] ----------------
__global__ void gather_kernel(const int* __restrict__ ids, const float* __restrict__ emb,
                              float* __restrict__ dec) {
    int bt = blockIdx.x;
    int d = threadIdx.x;
    dec[(size_t)bt * ND + d] = emb[(size_t)ids[bt] * ND + d];
}

// ---------------- qwq[p][o] = dot(q[p,:], w_q[o,:]) ----------------
__global__ void qwq_kernel(const float* __restrict__ q, const float* __restrict__ w_q,
                           float* __restrict__ qwq) {
    int p = blockIdx.x;
    int o = threadIdx.x;
    __shared__ float qs[ND];
    qs[o] = q[(size_t)p * ND + o];
    __syncthreads();
    const float4* wr = (const float4*)(w_q + (size_t)o * ND);
    float acc = 0.f;
    for (int k4 = 0; k4 < ND / 4; ++k4) {
        float4 w = wr[k4];
        int k = 4 * k4;
        acc += qs[k] * w.x + qs[k + 1] * w.y + qs[k + 2] * w.z + qs[k + 3] * w.w;
    }
    qwq[(size_t)p * ND + o] = acc;
}

// ---------------- base[b,f,o] = dot(f[b,f,:], w_f[o,:]) + qwq[f,o] ----------------
__global__ void base_kernel(const float* __restrict__ fin, const float* __restrict__ w_f,
                            const float* __restrict__ qwq, float* __restrict__ base) {
    int b = blockIdx.x / NTILE;
    int f0 = (blockIdx.x % NTILE) * RPB;
    int o = threadIdx.x;
    __shared__ float fs[RPB][ND];
    #pragma unroll
    for (int r = 0; r < RPB; ++r)
        fs[r][o] = fin[((size_t)(b * NF + f0 + r)) * ND + o];
    __syncthreads();
    float acc[RPB];
    #pragma unroll
    for (int r = 0; r < RPB; ++r) acc[r] = 0.f;
    const float4* wr = (const float4*)(w_f + (size_t)o * ND);
    for (int k4 = 0; k4 < ND / 4; ++k4) {
        float4 w = wr[k4];
        int k = 4 * k4;
        #pragma unroll
        for (int r = 0; r < RPB; ++r)
            acc[r] += fs[r][k] * w.x + fs[r][k + 1] * w.y + fs[r][k + 2] * w.z + fs[r][k + 3] * w.w;
    }
    #pragma unroll
    for (int r = 0; r < RPB; ++r)
        base[((size_t)(b * NF + f0 + r)) * ND + o] = acc[r] + qwq[(size_t)(f0 + r) * ND + o];
}

// ---------------- prep: reduce partials -> c,cp; build Z=[x_t,cp,h], ZP=[c,h] ----------------
__global__ void prep_kernel(int t,
                            const float* __restrict__ dec,
                            const float* __restrict__ cpart, const float* __restrict__ cppart,
                            const float* __restrict__ h,
                            float* __restrict__ Z, float* __restrict__ ZP) {
    int b = blockIdx.x;
    int d = threadIdx.x;
    float csum = 0.f, cpsum = 0.f;
    if (t > 0) {
        for (int tile = 0; tile < NTILE; ++tile) {
            csum  += cpart [((size_t)tile * NB + b) * ND + d];
            cpsum += cppart[((size_t)tile * NB + b) * ND + d];
        }
    }
    float hv = h[(size_t)b * ND + d];
    float xv = (t < NT) ? dec[((size_t)b * NT + t) * ND + d] : 0.0f;
    Z[(size_t)b * 768 + d]       = xv;
    Z[(size_t)b * 768 + 256 + d] = cpsum;
    Z[(size_t)b * 768 + 512 + d] = hv;
    ZP[(size_t)b * 512 + d]       = csum;
    ZP[(size_t)b * 512 + 256 + d] = hv;
}

// ---------------- gates + pred, row-parallel ----------------
// blocks 0..127: 8 gate rows each (1024 rows). blocks 128..159: 8 pred rows each.
// mode bit0: do gates; bit1: do pred (writes out[t-1]).
#define ZSTRIDE 769
#define ZPSTRIDE 513
__global__ void gates_kernel(int t, int mode,
                             const float* __restrict__ Z, const float* __restrict__ ZP,
                             const float* __restrict__ w_ih, const float* __restrict__ w_hh,
                             const float* __restrict__ w_g,
                             float* __restrict__ gatesT, float* __restrict__ out) {
    extern __shared__ float lds[];   // gates: w 8*768 then z 32*769 ; pred: w 8*512 then zp 32*513
    int bid = blockIdx.x;
    int tid = threadIdx.x;

    if (bid < 128) {
        if (!(mode & 1)) return;
        int j0 = bid * 8;
        float* wl = lds;              // [8][768]
        float* zl = lds + 8 * 768;    // [32][ZSTRIDE]
        // stage 8 combined weight rows: [w_ih[j](512) | w_hh[j](256)]
        float4* wl4 = (float4*)wl;
        for (int cc = 0; cc < 6; ++cc) {
            int idx4 = tid + cc * 256;          // < 1536
            int flat = idx4 * 4;
            int r = flat / 768;
            int col = flat - r * 768;
            float4 v;
            if (col < 512) v = *(const float4*)(w_ih + (size_t)(j0 + r) * 512 + col);
            else           v = *(const float4*)(w_hh + (size_t)(j0 + r) * 256 + (col - 512));
            wl4[idx4] = v;
        }
        // stage Z [32][768] -> stride 769
        for (int b = 0; b < NB; ++b)
            for (int k = tid; k < 768; k += 256)
                zl[b * ZSTRIDE + k] = Z[(size_t)b * 768 + k];
        __syncthreads();
        int r = tid >> 5;
        int b = tid & 31;
        const float4* wr4 = (const float4*)(wl + r * 768);
        const float* zb = zl + b * ZSTRIDE;
        float acc = 0.f;
        #pragma unroll 8
        for (int k4 = 0; k4 < 192; ++k4) {
            float4 w = wr4[k4];
            int k = 4 * k4;
            acc += w.x * zb[k] + w.y * zb[k + 1] + w.z * zb[k + 2] + w.w * zb[k + 3];
        }
        gatesT[(size_t)(j0 + r) * NB + b] = acc;
    } else {
        if (!(mode & 2)) return;
        int p0 = (bid - 128) * 8;
        float* wl = lds;              // [8][512]
        float* zl = lds + 8 * 512;    // [32][ZPSTRIDE]
        float4* wl4 = (float4*)wl;
        for (int cc = 0; cc < 4; ++cc) {
            int idx4 = tid + cc * 256;          // < 1024
            int flat = idx4 * 4;
            int r = flat >> 9;
            int col = flat & 511;
            wl4[idx4] = *(const float4*)(w_g + (size_t)(p0 + r) * 512 + col);
        }
        for (int b = 0; b < NB; ++b)
            for (int k = tid; k < 512; k += 256)
                zl[b * ZPSTRIDE + k] = ZP[(size_t)b * 512 + k];
        __syncthreads();
        int r = tid >> 5;
        int b = tid & 31;
        const float4* wr4 = (const float4*)(wl + r * 512);
        const float* zb = zl + b * ZPSTRIDE;
        float acc = 0.f;
        #pragma unroll 8
        for (int k4 = 0; k4 < 128; ++k4) {
            float4 w = wr4[k4];
            int k = 4 * k4;
            acc += w.x * zb[k] + w.y * zb[k + 1] + w.z * zb[k + 2] + w.w * zb[k + 3];
        }
        out[((size_t)b * NT + (t - 1)) * ND + p0 + r] = acc;
    }
}

// ---------------- cell update + hwh ----------------
__global__ void cell_hwh_kernel(const float* __restrict__ gatesT,
                                float* __restrict__ h, float* __restrict__ cell,
                                const float* __restrict__ w_h, float* __restrict__ hwh) {
    int b = blockIdx.x;
    int o = threadIdx.x;
    __shared__ float hn[ND];
    float gi = gatesT[(size_t)(0 * ND + o) * NB + b];
    float gf = gatesT[(size_t)(1 * ND + o) * NB + b];
    float gg = gatesT[(size_t)(2 * ND + o) * NB + b];
    float go = gatesT[(size_t)(3 * ND + o) * NB + b];
    float cold = cell[(size_t)b * ND + o];
    float cnew = sigmoidf_(gf) * cold + sigmoidf_(gi) * tanhf(gg);
    float hval = sigmoidf_(go) * tanhf(cnew);
    cell[(size_t)b * ND + o] = cnew;
    h[(size_t)b * ND + o] = hval;
    hn[o] = hval;
    __syncthreads();
    const float4* whr = (const float4*)(w_h + (size_t)o * ND);
    float a = 0.f;
    for (int k4 = 0; k4 < ND / 4; ++k4) {
        float4 w = whr[k4]; int k = 4 * k4;
        a += hn[k] * w.x + hn[k + 1] * w.y + hn[k + 2] * w.z + hn[k + 3] * w.w;
    }
    hwh[(size_t)b * ND + o] = a;
}

// ---------------- fused attention step (unchanged) ----------------
__global__ void attn_step_kernel(const float* __restrict__ base, float* __restrict__ sws,
                                 const float* __restrict__ fin, const float* __restrict__ q,
                                 const float* __restrict__ hwh,
                                 const float* __restrict__ w_e, const float* __restrict__ w_s,
                                 float* __restrict__ cpart, float* __restrict__ cppart) {
    int b = blockIdx.x / NTILE;
    int tile = blockIdx.x % NTILE;
    int f0 = tile * RPB;
    int o = threadIdx.x;

    __shared__ float hwh_s[ND];
    __shared__ float tin[RPB][ND];
    hwh_s[o] = hwh[(size_t)b * ND + o];

    float sval[RPB];
    #pragma unroll
    for (int r = 0; r < RPB; ++r) {
        size_t idx = ((size_t)(b * NF + f0 + r)) * ND + o;
        float sv = sws[idx];
        sval[r] = sv;
        tin[r][o] = tanhf(hwh_s[o] + base[idx] + sv);
    }
    __syncthreads();

    float acc[RPB];
    #pragma unroll
    for (int r = 0; r < RPB; ++r) acc[r] = 0.f;
    {
        const float4* wr = (const float4*)(w_e + (size_t)o * ND);
        for (int k4 = 0; k4 < ND / 4; ++k4) {
            float4 w = wr[k4]; int k = 4 * k4;
            #pragma unroll
            for (int r = 0; r < RPB; ++r)
                acc[r] += tin[r][k] * w.x + tin[r][k + 1] * w.y + tin[r][k + 2] * w.z + tin[r][k + 3] * w.w;
        }
    }
    __syncthreads();
    #pragma unroll
    for (int r = 0; r < RPB; ++r) tin[r][o] = acc[r];
    __syncthreads();

    int lane = o & 63, wv = o >> 6;
    for (int r = wv; r < RPB; r += 4) {
        float m = -1e30f;
        #pragma unroll
        for (int kk = lane; kk < ND; kk += 64) m = fmaxf(m, tin[r][kk]);
        #pragma unroll
        for (int off = 32; off >= 1; off >>= 1) m = fmaxf(m, __shfl_xor(m, off));
        float ssum = 0.f;
        #pragma unroll
        for (int kk = lane; kk < ND; kk += 64) {
            float ev = __expf(tin[r][kk] - m);
            tin[r][kk] = ev;
            ssum += ev;
        }
        #pragma unroll
        for (int off = 32; off >= 1; off >>= 1) ssum += __shfl_xor(ssum, off);
        float inv = 1.0f / ssum;
        #pragma unroll
        for (int kk = lane; kk < ND; kk += 64) tin[r][kk] *= inv;
    }
    __syncthreads();

    float pc = 0.f, pcp = 0.f;
    #pragma unroll
    for (int r = 0; r < RPB; ++r) {
        float a = tin[r][o];
        size_t idx = ((size_t)(b * NF + f0 + r)) * ND + o;
        float fv = fin[idx];
        float qv = q[(size_t)(f0 + r) * ND + o];
        pc += a * fv;
        pcp += a * (fv + qv);
    }
    cpart [((size_t)tile * NB + b) * ND + o] = pc;
    cppart[((size_t)tile * NB + b) * ND + o] = pcp;

    float acc2[RPB];
    #pragma unroll
    for (int r = 0; r < RPB; ++r) acc2[r] = 0.f;
    {
        const float4* wr = (const float4*)(w_s + (size_t)o * ND);
        for (int k4 = 0; k4 < ND / 4; ++k4) {
            float4 w = wr[k4]; int k = 4 * k4;
            #pragma unroll
            for (int r = 0; r < RPB; ++r)
                acc2[r] += tin[r][k] * w.x + tin[r][k + 1] * w.y + tin[r][k + 2] * w.z + tin[r][k + 3] * w.w;
        }
    }
    #pragma unroll
    for (int r = 0; r < RPB; ++r) {
        size_t idx = ((size_t)(b * NF + f0 + r)) * ND + o;
        sws[idx] = sval[r] + acc2[r];
    }
}

extern "C" void kernel_launch(void* const* d_in, const int* in_sizes, int n_in,
                              void* d_out, int out_size, void* d_ws, size_t ws_size,
                              hipStream_t stream) {
    const float* fin  = (const float*)d_in[0];
    const int*   ids  = (const int*)  d_in[1];
    const float* emb  = (const float*)d_in[2];
    const float* w_e  = (const float*)d_in[3];
    const float* w_h  = (const float*)d_in[4];
    const float* w_f  = (const float*)d_in[5];
    const float* w_q  = (const float*)d_in[6];
    const float* w_s  = (const float*)d_in[7];
    const float* w_g  = (const float*)d_in[8];
    const float* w_ih = (const float*)d_in[9];
    const float* w_hh = (const float*)d_in[10];
    float* out = (float*)d_out;
    float* ws  = (float*)d_ws;

    size_t off = 0;
    float* q      = ws + off; off += (size_t)NF * ND;        // 131072
    float* scratch= ws + off; off += (size_t)NF * ND;        // 131072 (qwq, then Z/ZP/gatesT)
    float* dec    = ws + off; off += (size_t)NB * NT * ND;   // 262144
    float* base   = ws + off; off += (size_t)NB * NF * ND;   // 4194304
    float* sws    = ws + off; off += (size_t)NB * NF * ND;   // 4194304
    float* h      = ws + off; off += (size_t)NB * ND;
    float* cell   = ws + off; off += (size_t)NB * ND;
    float* hwh    = ws + off; off += (size_t)NB * ND;
    float* cpart  = ws + off; off += (size_t)NTILE * NB * ND;
    float* cppart = ws + off; off += (size_t)NTILE * NB * ND;

    // reuse of scratch region after base_kernel: Z(24576) | ZP(16384) | gatesT(32768)
    float* qwq    = scratch;
    float* Z      = scratch;
    float* ZP     = scratch + 24576;
    float* gatesT = scratch + 24576 + 16384;

    hipMemsetAsync(sws, 0, sizeof(float) * (size_t)NB * NF * ND, stream);
    hipMemsetAsync(h, 0, sizeof(float) * NB * ND, stream);
    hipMemsetAsync(cell, 0, sizeof(float) * NB * ND, stream);

    pe_kernel<<<NF, ND, 0, stream>>>(q);
    gather_kernel<<<NB * NT, ND, 0, stream>>>(ids, emb, dec);
    qwq_kernel<<<NF, ND, 0, stream>>>(q, w_q, qwq);
    base_kernel<<<NB * NTILE, ND, 0, stream>>>(fin, w_f, qwq, base);

    const size_t gates_lds = (size_t)(8 * 768 + NB * ZSTRIDE) * sizeof(float);  // 123008 B

    for (int t = 0; t < NT; ++t) {
        int mode = (t > 0) ? 3 : 1;
        prep_kernel<<<NB, ND, 0, stream>>>(t, dec, cpart, cppart, h, Z, ZP);
        gates_kernel<<<160, ND, gates_lds, stream>>>(t, mode, Z, ZP, w_ih, w_hh, w_g, gatesT, out);
        cell_hwh_kernel<<<NB, ND, 0, stream>>>(gatesT, h, cell, w_h, hwh);
        attn_step_kernel<<<NB * NTILE, ND, 0, stream>>>(base, sws, fin, q, hwh,
                                                        w_e, w_s, cpart, cppart);
    }
    // final pred for t = NT-1
    prep_kernel<<<NB, ND, 0, stream>>>(NT, dec, cpart, cppart, h, Z, ZP);
    gates_kernel<<<160, ND, gates_lds, stream>>>(NT, 2, Z, ZP, w_ih, w_hh, w_g, gatesT, out);
}

// Round 6
// 3138.773 us; speedup vs baseline: 4.1681x; 1.9697x over previous
//
#include <hip/hip_runtime.h>
#include <math.h>

#define NB 32      // batch
#define NF 512     // feature_size (source positions)
#define ND 256     // d_model
#define NT 32      // decode steps
#define RPB 32     // rows (f positions) per attention block
#define NTILE (NF / RPB)   // 16 f-tiles

typedef __attribute__((ext_vector_type(8))) short bf16x8;
typedef __attribute__((ext_vector_type(4))) float f32x4;

__device__ __forceinline__ float sigmoidf_(float x) { return 1.0f / (1.0f + __expf(-x)); }

__device__ __forceinline__ short f2bf(float x) {
    union { float f; unsigned u; } v; v.f = x;
    unsigned r = (v.u + 0x7FFF + ((v.u >> 16) & 1)) >> 16;
    return (short)r;
}

// ---------------- positional encoding q[F][D] ----------------
__global__ void pe_kernel(float* __restrict__ q) {
    int p = blockIdx.x;
    int d = threadIdx.x;
    float i2 = (float)((d >> 1) << 1);
    float rate = expf(-9.210340371976184f * (i2 / (float)ND));
    float ang = (float)p * rate;
    q[p * ND + d] = (d & 1) ? cosf(ang) : sinf(ang);
}

// ---------------- dec = emb[ids]  [B*T][D] ----------------
__global__ void gather_kernel(const int* __restrict__ ids, const float* __restrict__ emb,
                              float* __restrict__ dec) {
    int bt = blockIdx.x;
    int d = threadIdx.x;
    dec[(size_t)bt * ND + d] = emb[(size_t)ids[bt] * ND + d];
}

// ---------------- fp32 -> bf16 weight convert ----------------
__global__ void wcvt_kernel(const float* __restrict__ w, short* __restrict__ wb, int n) {
    int i = blockIdx.x * 256 + threadIdx.x;
    if (i < n) wb[i] = f2bf(w[i]);
}

// ---------------- qwq[p][o] = dot(q[p,:], w_q[o,:]) ----------------
__global__ void qwq_kernel(const float* __restrict__ q, const float* __restrict__ w_q,
                           float* __restrict__ qwq) {
    int p = blockIdx.x;
    int o = threadIdx.x;
    __shared__ float qs[ND];
    qs[o] = q[(size_t)p * ND + o];
    __syncthreads();
    const float4* wr = (const float4*)(w_q + (size_t)o * ND);
    float acc = 0.f;
    for (int k4 = 0; k4 < ND / 4; ++k4) {
        float4 w = wr[k4];
        int k = 4 * k4;
        acc += qs[k] * w.x + qs[k + 1] * w.y + qs[k + 2] * w.z + qs[k + 3] * w.w;
    }
    qwq[(size_t)p * ND + o] = acc;
}

// ---------------- base[b,f,o] = dot(f[b,f,:], w_f[o,:]) + qwq[f,o] ----------------
__global__ void base_kernel(const float* __restrict__ fin, const float* __restrict__ w_f,
                            const float* __restrict__ qwq, float* __restrict__ base) {
    int b = blockIdx.x / NTILE;
    int f0 = (blockIdx.x % NTILE) * RPB;
    int o = threadIdx.x;
    __shared__ float fs[RPB][ND];
    #pragma unroll
    for (int r = 0; r < RPB; ++r)
        fs[r][o] = fin[((size_t)(b * NF + f0 + r)) * ND + o];
    __syncthreads();
    float acc[RPB];
    #pragma unroll
    for (int r = 0; r < RPB; ++r) acc[r] = 0.f;
    const float4* wr = (const float4*)(w_f + (size_t)o * ND);
    for (int k4 = 0; k4 < ND / 4; ++k4) {
        float4 w = wr[k4];
        int k = 4 * k4;
        #pragma unroll
        for (int r = 0; r < RPB; ++r)
            acc[r] += fs[r][k] * w.x + fs[r][k + 1] * w.y + fs[r][k + 2] * w.z + fs[r][k + 3] * w.w;
    }
    #pragma unroll
    for (int r = 0; r < RPB; ++r)
        base[((size_t)(b * NF + f0 + r)) * ND + o] = acc[r] + qwq[(size_t)(f0 + r) * ND + o];
}

// ---------------- prep: reduce partials -> c,cp; build Z=[x_t,cp,h], ZP=[c,h] ----------------
__global__ void prep_kernel(int t,
                            const float* __restrict__ dec,
                            const float* __restrict__ cpart, const float* __restrict__ cppart,
                            const float* __restrict__ h,
                            float* __restrict__ Z, float* __restrict__ ZP) {
    int b = blockIdx.x;
    int d = threadIdx.x;
    float csum = 0.f, cpsum = 0.f;
    if (t > 0) {
        for (int tile = 0; tile < NTILE; ++tile) {
            csum  += cpart [((size_t)tile * NB + b) * ND + d];
            cpsum += cppart[((size_t)tile * NB + b) * ND + d];
        }
    }
    float hv = h[(size_t)b * ND + d];
    float xv = (t < NT) ? dec[((size_t)b * NT + t) * ND + d] : 0.0f;
    Z[(size_t)b * 768 + d]       = xv;
    Z[(size_t)b * 768 + 256 + d] = cpsum;
    Z[(size_t)b * 768 + 512 + d] = hv;
    ZP[(size_t)b * 512 + d]       = csum;
    ZP[(size_t)b * 512 + 256 + d] = hv;
}

// ---------------- gates + pred, row-parallel ----------------
#define ZSTRIDE 769
#define ZPSTRIDE 513
__global__ void gates_kernel(int t, int mode,
                             const float* __restrict__ Z, const float* __restrict__ ZP,
                             const float* __restrict__ w_ih, const float* __restrict__ w_hh,
                             const float* __restrict__ w_g,
                             float* __restrict__ gatesT, float* __restrict__ out) {
    extern __shared__ float lds[];
    int bid = blockIdx.x;
    int tid = threadIdx.x;

    if (bid < 128) {
        if (!(mode & 1)) return;
        int j0 = bid * 8;
        float* wl = lds;              // [8][768]
        float* zl = lds + 8 * 768;    // [32][ZSTRIDE]
        float4* wl4 = (float4*)wl;
        for (int cc = 0; cc < 6; ++cc) {
            int idx4 = tid + cc * 256;
            int flat = idx4 * 4;
            int r = flat / 768;
            int col = flat - r * 768;
            float4 v;
            if (col < 512) v = *(const float4*)(w_ih + (size_t)(j0 + r) * 512 + col);
            else           v = *(const float4*)(w_hh + (size_t)(j0 + r) * 256 + (col - 512));
            wl4[idx4] = v;
        }
        for (int b = 0; b < NB; ++b)
            for (int k = tid; k < 768; k += 256)
                zl[b * ZSTRIDE + k] = Z[(size_t)b * 768 + k];
        __syncthreads();
        int r = tid >> 5;
        int b = tid & 31;
        const float4* wr4 = (const float4*)(wl + r * 768);
        const float* zb = zl + b * ZSTRIDE;
        float acc = 0.f;
        #pragma unroll 8
        for (int k4 = 0; k4 < 192; ++k4) {
            float4 w = wr4[k4];
            int k = 4 * k4;
            acc += w.x * zb[k] + w.y * zb[k + 1] + w.z * zb[k + 2] + w.w * zb[k + 3];
        }
        gatesT[(size_t)(j0 + r) * NB + b] = acc;
    } else {
        if (!(mode & 2)) return;
        int p0 = (bid - 128) * 8;
        float* wl = lds;              // [8][512]
        float* zl = lds + 8 * 512;    // [32][ZPSTRIDE]
        float4* wl4 = (float4*)wl;
        for (int cc = 0; cc < 4; ++cc) {
            int idx4 = tid + cc * 256;
            int flat = idx4 * 4;
            int r = flat >> 9;
            int col = flat & 511;
            wl4[idx4] = *(const float4*)(w_g + (size_t)(p0 + r) * 512 + col);
        }
        for (int b = 0; b < NB; ++b)
            for (int k = tid; k < 512; k += 256)
                zl[b * ZPSTRIDE + k] = ZP[(size_t)b * 512 + k];
        __syncthreads();
        int r = tid >> 5;
        int b = tid & 31;
        const float4* wr4 = (const float4*)(wl + r * 512);
        const float* zb = zl + b * ZPSTRIDE;
        float acc = 0.f;
        #pragma unroll 8
        for (int k4 = 0; k4 < 128; ++k4) {
            float4 w = wr4[k4];
            int k = 4 * k4;
            acc += w.x * zb[k] + w.y * zb[k + 1] + w.z * zb[k + 2] + w.w * zb[k + 3];
        }
        out[((size_t)b * NT + (t - 1)) * ND + p0 + r] = acc;
    }
}

// ---------------- cell update + hwh ----------------
__global__ void cell_hwh_kernel(const float* __restrict__ gatesT,
                                float* __restrict__ h, float* __restrict__ cell,
                                const float* __restrict__ w_h, float* __restrict__ hwh) {
    int b = blockIdx.x;
    int o = threadIdx.x;
    __shared__ float hn[ND];
    float gi = gatesT[(size_t)(0 * ND + o) * NB + b];
    float gf = gatesT[(size_t)(1 * ND + o) * NB + b];
    float gg = gatesT[(size_t)(2 * ND + o) * NB + b];
    float go = gatesT[(size_t)(3 * ND + o) * NB + b];
    float cold = cell[(size_t)b * ND + o];
    float cnew = sigmoidf_(gf) * cold + sigmoidf_(gi) * tanhf(gg);
    float hval = sigmoidf_(go) * tanhf(cnew);
    cell[(size_t)b * ND + o] = cnew;
    h[(size_t)b * ND + o] = hval;
    hn[o] = hval;
    __syncthreads();
    const float4* whr = (const float4*)(w_h + (size_t)o * ND);
    float a = 0.f;
    for (int k4 = 0; k4 < ND / 4; ++k4) {
        float4 w = whr[k4]; int k = 4 * k4;
        a += hn[k] * w.x + hn[k + 1] * w.y + hn[k + 2] * w.z + hn[k + 3] * w.w;
    }
    hwh[(size_t)b * ND + o] = a;
}

// ---------------- fused attention step, MFMA version ----------------
// A-tile LDS (bf16, XOR-swizzled): element (r,k) at byte (r*512 + k*2) ^ ((r&7)<<4)
// e LDS fp32 stride 257 (conflict-free).
__global__ void attn_step_kernel(const float* __restrict__ base, float* __restrict__ sws,
                                 const float* __restrict__ fin, const float* __restrict__ q,
                                 const float* __restrict__ hwh,
                                 const short* __restrict__ w_e_bf, const short* __restrict__ w_s_bf,
                                 float* __restrict__ cpart, float* __restrict__ cppart) {
    int b = blockIdx.x / NTILE;
    int tile = blockIdx.x % NTILE;
    int f0 = tile * RPB;
    int tid = threadIdx.x;
    int l = tid & 63;        // lane
    int wv = tid >> 6;       // wave 0..3

    __shared__ __align__(16) short tin_bf[RPB * ND];   // 16 KB, swizzled
    __shared__ float e_lds[RPB * 257];                 // 32.9 KB

    // ---- phase 1: tin = tanh(hwh + base + sws), bf16 -> swizzled LDS ----
    {
        float hv = hwh[(size_t)b * ND + tid];
        char* tb = (char*)tin_bf;
        #pragma unroll 8
        for (int r = 0; r < RPB; ++r) {
            size_t idx = ((size_t)(b * NF + f0 + r)) * ND + tid;
            float tv = tanhf(hv + base[idx] + sws[idx]);
            int byte = (r * 512 + tid * 2) ^ ((r & 7) << 4);
            *(short*)(tb + byte) = f2bf(tv);
        }
    }
    __syncthreads();

    // ---- phase 2: e = tin @ w_e^T via MFMA; wave wv owns cols [wv*64, wv*64+64) ----
    int o0 = wv * 64;
    int arow_lo = l & 15, kgrp = (l >> 4) * 8;
    f32x4 acc[2][4];
    #pragma unroll
    for (int mt = 0; mt < 2; ++mt)
        #pragma unroll
        for (int nt = 0; nt < 4; ++nt)
            acc[mt][nt] = (f32x4)0.f;
    {
        const char* tb = (const char*)tin_bf;
        #pragma unroll
        for (int ks = 0; ks < 8; ++ks) {
            int kb = ks * 32 + kgrp;
            bf16x8 afr[2];
            #pragma unroll
            for (int mt = 0; mt < 2; ++mt) {
                int row = mt * 16 + arow_lo;
                int byte = (row * 512 + kb * 2) ^ ((row & 7) << 4);
                afr[mt] = *(const bf16x8*)(tb + byte);
            }
            #pragma unroll
            for (int nt = 0; nt < 4; ++nt) {
                int o = o0 + nt * 16 + arow_lo;
                bf16x8 bfr = *(const bf16x8*)(w_e_bf + (size_t)o * ND + kb);
                #pragma unroll
                for (int mt = 0; mt < 2; ++mt)
                    acc[mt][nt] = __builtin_amdgcn_mfma_f32_16x16x32_bf16(afr[mt], bfr, acc[mt][nt], 0, 0, 0);
            }
        }
    }
    // write e to LDS (C-layout: col=l&15, row=(l>>4)*4+reg)
    {
        int crow = (l >> 4) * 4, ccol = l & 15;
        #pragma unroll
        for (int mt = 0; mt < 2; ++mt)
            #pragma unroll
            for (int nt = 0; nt < 4; ++nt) {
                int col = o0 + nt * 16 + ccol;
                #pragma unroll
                for (int reg = 0; reg < 4; ++reg)
                    e_lds[(mt * 16 + crow + reg) * 257 + col] = acc[mt][nt][reg];
            }
    }
    __syncthreads();

    // ---- phase 3: softmax over cols per row (fp32), alpha -> e_lds (fp32) + tin_bf (bf16) ----
    {
        char* tb = (char*)tin_bf;
        for (int r = wv * 8; r < wv * 8 + 8; ++r) {
            float* er = e_lds + r * 257;
            float m = -1e30f;
            #pragma unroll
            for (int j = 0; j < 4; ++j) m = fmaxf(m, er[l + 64 * j]);
            #pragma unroll
            for (int off = 32; off >= 1; off >>= 1) m = fmaxf(m, __shfl_xor(m, off));
            float ssum = 0.f;
            float ev[4];
            #pragma unroll
            for (int j = 0; j < 4; ++j) {
                ev[j] = __expf(er[l + 64 * j] - m);
                ssum += ev[j];
            }
            #pragma unroll
            for (int off = 32; off >= 1; off >>= 1) ssum += __shfl_xor(ssum, off);
            float inv = 1.0f / ssum;
            #pragma unroll
            for (int j = 0; j < 4; ++j) {
                float a = ev[j] * inv;
                int kk = l + 64 * j;
                er[kk] = a;
                int byte = (r * 512 + kk * 2) ^ ((r & 7) << 4);
                *(short*)(tb + byte) = f2bf(a);
            }
        }
    }
    __syncthreads();

    // ---- phase 4: c/cp partials from fp32 alpha (thread tid = col o) ----
    {
        float pc = 0.f, pcp = 0.f;
        #pragma unroll 8
        for (int r = 0; r < RPB; ++r) {
            float a = e_lds[r * 257 + tid];
            size_t idx = ((size_t)(b * NF + f0 + r)) * ND + tid;
            float fv = fin[idx];
            float qv = q[(size_t)(f0 + r) * ND + tid];
            pc += a * fv;
            pcp += a * (fv + qv);
        }
        cpart [((size_t)tile * NB + b) * ND + tid] = pc;
        cppart[((size_t)tile * NB + b) * ND + tid] = pcp;
    }

    // ---- phase 5: sws += alpha @ w_s^T via MFMA ----
    {
        f32x4 acc2[2][4];
        #pragma unroll
        for (int mt = 0; mt < 2; ++mt)
            #pragma unroll
            for (int nt = 0; nt < 4; ++nt)
                acc2[mt][nt] = (f32x4)0.f;
        const char* tb = (const char*)tin_bf;
        #pragma unroll
        for (int ks = 0; ks < 8; ++ks) {
            int kb = ks * 32 + kgrp;
            bf16x8 afr[2];
            #pragma unroll
            for (int mt = 0; mt < 2; ++mt) {
                int row = mt * 16 + arow_lo;
                int byte = (row * 512 + kb * 2) ^ ((row & 7) << 4);
                afr[mt] = *(const bf16x8*)(tb + byte);
            }
            #pragma unroll
            for (int nt = 0; nt < 4; ++nt) {
                int o = o0 + nt * 16 + arow_lo;
                bf16x8 bfr = *(const bf16x8*)(w_s_bf + (size_t)o * ND + kb);
                #pragma unroll
                for (int mt = 0; mt < 2; ++mt)
                    acc2[mt][nt] = __builtin_amdgcn_mfma_f32_16x16x32_bf16(afr[mt], bfr, acc2[mt][nt], 0, 0, 0);
            }
        }
        int crow = (l >> 4) * 4, ccol = l & 15;
        #pragma unroll
        for (int mt = 0; mt < 2; ++mt)
            #pragma unroll
            for (int nt = 0; nt < 4; ++nt) {
                int col = o0 + nt * 16 + ccol;
                #pragma unroll
                for (int reg = 0; reg < 4; ++reg) {
                    int row = mt * 16 + crow + reg;
                    size_t idx = ((size_t)(b * NF + f0 + row)) * ND + col;
                    sws[idx] += acc2[mt][nt][reg];
                }
            }
    }
}

extern "C" void kernel_launch(void* const* d_in, const int* in_sizes, int n_in,
                              void* d_out, int out_size, void* d_ws, size_t ws_size,
                              hipStream_t stream) {
    const float* fin  = (const float*)d_in[0];
    const int*   ids  = (const int*)  d_in[1];
    const float* emb  = (const float*)d_in[2];
    const float* w_e  = (const float*)d_in[3];
    const float* w_h  = (const float*)d_in[4];
    const float* w_f  = (const float*)d_in[5];
    const float* w_q  = (const float*)d_in[6];
    const float* w_s  = (const float*)d_in[7];
    const float* w_g  = (const float*)d_in[8];
    const float* w_ih = (const float*)d_in[9];
    const float* w_hh = (const float*)d_in[10];
    float* out = (float*)d_out;
    float* ws  = (float*)d_ws;

    size_t off = 0;
    float* q      = ws + off; off += (size_t)NF * ND;        // 131072
    float* scratch= ws + off; off += (size_t)NF * ND;        // 131072 (qwq, then Z/ZP/gatesT)
    float* dec    = ws + off; off += (size_t)NB * NT * ND;   // 262144
    float* base   = ws + off; off += (size_t)NB * NF * ND;   // 4194304
    float* sws    = ws + off; off += (size_t)NB * NF * ND;   // 4194304
    float* h      = ws + off; off += (size_t)NB * ND;
    float* cell   = ws + off; off += (size_t)NB * ND;
    float* hwh    = ws + off; off += (size_t)NB * ND;
    float* cpart  = ws + off; off += (size_t)NTILE * NB * ND;
    float* cppart = ws + off; off += (size_t)NTILE * NB * ND;
    short* w_e_bf = (short*)(ws + off); off += (size_t)ND * ND / 2;   // 65536 bf16
    short* w_s_bf = (short*)(ws + off); off += (size_t)ND * ND / 2;

    float* qwq    = scratch;
    float* Z      = scratch;
    float* ZP     = scratch + 24576;
    float* gatesT = scratch + 24576 + 16384;

    hipMemsetAsync(sws, 0, sizeof(float) * (size_t)NB * NF * ND, stream);
    hipMemsetAsync(h, 0, sizeof(float) * NB * ND, stream);
    hipMemsetAsync(cell, 0, sizeof(float) * NB * ND, stream);

    pe_kernel<<<NF, ND, 0, stream>>>(q);
    gather_kernel<<<NB * NT, ND, 0, stream>>>(ids, emb, dec);
    wcvt_kernel<<<ND * ND / 256, 256, 0, stream>>>(w_e, w_e_bf, ND * ND);
    wcvt_kernel<<<ND * ND / 256, 256, 0, stream>>>(w_s, w_s_bf, ND * ND);
    qwq_kernel<<<NF, ND, 0, stream>>>(q, w_q, qwq);
    base_kernel<<<NB * NTILE, ND, 0, stream>>>(fin, w_f, qwq, base);

    const size_t gates_lds = (size_t)(8 * 768 + NB * ZSTRIDE) * sizeof(float);  // 123008 B

    for (int t = 0; t < NT; ++t) {
        int mode = (t > 0) ? 3 : 1;
        prep_kernel<<<NB, ND, 0, stream>>>(t, dec, cpart, cppart, h, Z, ZP);
        gates_kernel<<<160, ND, gates_lds, stream>>>(t, mode, Z, ZP, w_ih, w_hh, w_g, gatesT, out);
        cell_hwh_kernel<<<NB, ND, 0, stream>>>(gatesT, h, cell, w_h, hwh);
        attn_step_kernel<<<NB * NTILE, ND, 0, stream>>>(base, sws, fin, q, hwh,
                                                        w_e_bf, w_s_bf, cpart, cppart);
    }
    // final pred for t = NT-1
    prep_kernel<<<NB, ND, 0, stream>>>(NT, dec, cpart, cppart, h, Z, ZP);
    gates_kernel<<<160, ND, gates_lds, stream>>>(NT, 2, Z, ZP, w_ih, w_hh, w_g, gatesT, out);
}

// Round 8
// 3049.728 us; speedup vs baseline: 4.2898x; 1.0292x over previous
//
#include <hip/hip_runtime.h>
#include <math.h>

#define NB 32      // batch
#define NF 512     // feature_size (source positions)
#define ND 256     // d_model
#define NT 32      // decode steps
#define RPB 32     // rows (f positions) per attention block
#define NTILE (NF / RPB)   // 16 f-tiles

typedef __attribute__((ext_vector_type(8))) short bf16x8;
typedef __attribute__((ext_vector_type(4))) float f32x4;

__device__ __forceinline__ float sigmoidf_(float x) { return 1.0f / (1.0f + __expf(-x)); }

__device__ __forceinline__ short f2bf(float x) {
    union { float f; unsigned u; } v; v.f = x;
    unsigned r = (v.u + 0x7FFF + ((v.u >> 16) & 1)) >> 16;
    return (short)r;
}

// ---------------- positional encoding q[F][D] ----------------
__global__ void pe_kernel(float* __restrict__ q) {
    int p = blockIdx.x;
    int d = threadIdx.x;
    float i2 = (float)((d >> 1) << 1);
    float rate = expf(-9.210340371976184f * (i2 / (float)ND));
    float ang = (float)p * rate;
    q[p * ND + d] = (d & 1) ? cosf(ang) : sinf(ang);
}

// ---------------- dec = emb[ids]  [B*T][D] ----------------
__global__ void gather_kernel(const int* __restrict__ ids, const float* __restrict__ emb,
                              float* __restrict__ dec) {
    int bt = blockIdx.x;
    int d = threadIdx.x;
    dec[(size_t)bt * ND + d] = emb[(size_t)ids[bt] * ND + d];
}

// ---------------- fp32 -> bf16 weight convert ----------------
__global__ void wcvt_kernel(const float* __restrict__ w, short* __restrict__ wb, int n) {
    int i = blockIdx.x * 256 + threadIdx.x;
    if (i < n) wb[i] = f2bf(w[i]);
}

// ---------------- qwq[p][o] = dot(q[p,:], w_q[o,:]) ----------------
__global__ void qwq_kernel(const float* __restrict__ q, const float* __restrict__ w_q,
                           float* __restrict__ qwq) {
    int p = blockIdx.x;
    int o = threadIdx.x;
    __shared__ float qs[ND];
    qs[o] = q[(size_t)p * ND + o];
    __syncthreads();
    const float4* wr = (const float4*)(w_q + (size_t)o * ND);
    float acc = 0.f;
    for (int k4 = 0; k4 < ND / 4; ++k4) {
        float4 w = wr[k4];
        int k = 4 * k4;
        acc += qs[k] * w.x + qs[k + 1] * w.y + qs[k + 2] * w.z + qs[k + 3] * w.w;
    }
    qwq[(size_t)p * ND + o] = acc;
}

// ---------------- bsum[b,f,o] = dot(f[b,f,:], w_f[o,:]) + qwq[f,o]  (base, mutated later) ----------------
__global__ void base_kernel(const float* __restrict__ fin, const float* __restrict__ w_f,
                            const float* __restrict__ qwq, float* __restrict__ bsum) {
    int b = blockIdx.x / NTILE;
    int f0 = (blockIdx.x % NTILE) * RPB;
    int o = threadIdx.x;
    __shared__ float fs[RPB][ND];
    #pragma unroll
    for (int r = 0; r < RPB; ++r)
        fs[r][o] = fin[((size_t)(b * NF + f0 + r)) * ND + o];
    __syncthreads();
    float acc[RPB];
    #pragma unroll
    for (int r = 0; r < RPB; ++r) acc[r] = 0.f;
    const float4* wr = (const float4*)(w_f + (size_t)o * ND);
    for (int k4 = 0; k4 < ND / 4; ++k4) {
        float4 w = wr[k4];
        int k = 4 * k4;
        #pragma unroll
        for (int r = 0; r < RPB; ++r)
            acc[r] += fs[r][k] * w.x + fs[r][k + 1] * w.y + fs[r][k + 2] * w.z + fs[r][k + 3] * w.w;
    }
    #pragma unroll
    for (int r = 0; r < RPB; ++r)
        bsum[((size_t)(b * NF + f0 + r)) * ND + o] = acc[r] + qwq[(size_t)(f0 + r) * ND + o];
}

// ---------------- gates + pred, with inline Z/ZP construction (prep fused) ----------------
#define ZSTRIDE 769
#define ZPSTRIDE 513
__global__ void gates_kernel(int t, int mode,
                             const float* __restrict__ dec,
                             const float* __restrict__ cpart, const float* __restrict__ cppart,
                             const float* __restrict__ h,
                             const float* __restrict__ w_ih, const float* __restrict__ w_hh,
                             const float* __restrict__ w_g,
                             float* __restrict__ gatesT, float* __restrict__ out) {
    extern __shared__ float lds[];
    int bid = blockIdx.x;
    int tid = threadIdx.x;

    if (bid < 128) {
        if (!(mode & 1)) return;
        int j0 = bid * 8;
        float* wl = lds;              // [8][768]
        float* zl = lds + 8 * 768;    // [32][ZSTRIDE]
        float4* wl4 = (float4*)wl;
        for (int cc = 0; cc < 6; ++cc) {
            int idx4 = tid + cc * 256;
            int flat = idx4 * 4;
            int r = flat / 768;
            int col = flat - r * 768;
            float4 v;
            if (col < 512) v = *(const float4*)(w_ih + (size_t)(j0 + r) * 512 + col);
            else           v = *(const float4*)(w_hh + (size_t)(j0 + r) * 256 + (col - 512));
            wl4[idx4] = v;
        }
        // inline prep: Z[b] = [x_t | cpsum | h]
        for (int b = 0; b < NB; ++b) {
            int d = tid;
            float xv = (t < NT) ? dec[((size_t)b * NT + t) * ND + d] : 0.f;
            float cpsum = 0.f;
            if (t > 0) {
                #pragma unroll
                for (int tl = 0; tl < NTILE; ++tl)
                    cpsum += cppart[((size_t)tl * NB + b) * ND + d];
            }
            float hv = h[(size_t)b * ND + d];
            zl[b * ZSTRIDE + d]       = xv;
            zl[b * ZSTRIDE + 256 + d] = cpsum;
            zl[b * ZSTRIDE + 512 + d] = hv;
        }
        __syncthreads();
        int r = tid >> 5;
        int b = tid & 31;
        const float4* wr4 = (const float4*)(wl + r * 768);
        const float* zb = zl + b * ZSTRIDE;
        float acc = 0.f;
        #pragma unroll 8
        for (int k4 = 0; k4 < 192; ++k4) {
            float4 w = wr4[k4];
            int k = 4 * k4;
            acc += w.x * zb[k] + w.y * zb[k + 1] + w.z * zb[k + 2] + w.w * zb[k + 3];
        }
        gatesT[(size_t)(j0 + r) * NB + b] = acc;
    } else {
        if (!(mode & 2)) return;
        int p0 = (bid - 128) * 8;
        float* wl = lds;              // [8][512]
        float* zl = lds + 8 * 512;    // [32][ZPSTRIDE]
        float4* wl4 = (float4*)wl;
        for (int cc = 0; cc < 4; ++cc) {
            int idx4 = tid + cc * 256;
            int flat = idx4 * 4;
            int r = flat >> 9;
            int col = flat & 511;
            wl4[idx4] = *(const float4*)(w_g + (size_t)(p0 + r) * 512 + col);
        }
        // inline prep: ZP[b] = [csum | h]
        for (int b = 0; b < NB; ++b) {
            float csum = 0.f;
            #pragma unroll
            for (int tl = 0; tl < NTILE; ++tl)
                csum += cpart[((size_t)tl * NB + b) * ND + tid];
            zl[b * ZPSTRIDE + tid]       = csum;
            zl[b * ZPSTRIDE + 256 + tid] = h[(size_t)b * ND + tid];
        }
        __syncthreads();
        int r = tid >> 5;
        int b = tid & 31;
        const float4* wr4 = (const float4*)(wl + r * 512);
        const float* zb = zl + b * ZPSTRIDE;
        float acc = 0.f;
        #pragma unroll 8
        for (int k4 = 0; k4 < 128; ++k4) {
            float4 w = wr4[k4];
            int k = 4 * k4;
            acc += w.x * zb[k] + w.y * zb[k + 1] + w.z * zb[k + 2] + w.w * zb[k + 3];
        }
        out[((size_t)b * NT + (t - 1)) * ND + p0 + r] = acc;
    }
}

// ---------------- cell update + hwh ----------------
__global__ void cell_hwh_kernel(const float* __restrict__ gatesT,
                                float* __restrict__ h, float* __restrict__ cell,
                                const float* __restrict__ w_h, float* __restrict__ hwh) {
    int b = blockIdx.x;
    int o = threadIdx.x;
    __shared__ float hn[ND];
    float gi = gatesT[(size_t)(0 * ND + o) * NB + b];
    float gf = gatesT[(size_t)(1 * ND + o) * NB + b];
    float gg = gatesT[(size_t)(2 * ND + o) * NB + b];
    float go = gatesT[(size_t)(3 * ND + o) * NB + b];
    float cold = cell[(size_t)b * ND + o];
    float cnew = sigmoidf_(gf) * cold + sigmoidf_(gi) * tanhf(gg);
    float hval = sigmoidf_(go) * tanhf(cnew);
    cell[(size_t)b * ND + o] = cnew;
    h[(size_t)b * ND + o] = hval;
    hn[o] = hval;
    __syncthreads();
    const float4* whr = (const float4*)(w_h + (size_t)o * ND);
    float a = 0.f;
    for (int k4 = 0; k4 < ND / 4; ++k4) {
        float4 w = whr[k4]; int k = 4 * k4;
        a += hn[k] * w.x + hn[k + 1] * w.y + hn[k + 2] * w.z + hn[k + 3] * w.w;
    }
    hwh[(size_t)b * ND + o] = a;
}

// ---------------- fused attention step, MFMA + in-register softmax ----------------
// C-fragment mapping (m89-verified, validated round 6): lane l, acc[mt][nt][reg]
//   row = mt*16 + (l>>4)*4 + reg   (f-position within tile)
//   col = wv*64 + nt*16 + (l&15)   (o dimension)
// A/B-fragment mapping: lane l supplies row/col l&15, k = (l>>4)*8 + j.
// tin_bf swizzle: element (r,k) at byte (r*512 + k*2) ^ ((r&7)<<4).
__global__ void attn_step_kernel(float* __restrict__ bsum,
                                 const float* __restrict__ fin, const float* __restrict__ q,
                                 const float* __restrict__ hwh,
                                 const short* __restrict__ w_e_bf, const short* __restrict__ w_s_bf,
                                 float* __restrict__ cpart, float* __restrict__ cppart) {
    int b = blockIdx.x / NTILE;
    int tile = blockIdx.x % NTILE;
    int f0 = tile * RPB;
    int tid = threadIdx.x;
    int l = tid & 63;
    int wv = tid >> 6;

    __shared__ __align__(16) short tin_bf[RPB * ND];   // 16 KB, swizzled
    __shared__ float sred[RPB][5];                     // cross-wave row-sum partials

    int o0 = wv * 64;
    int c15 = l & 15;
    int g = l >> 4;
    int kgrp = g * 8;
    char* tb = (char*)tin_bf;

    // ---- phase 1: tin = tanh(hwh + bsum) in C-layout; keep bsum in regs; bf16 -> swizzled LDS ----
    float bsv[2][4][4];   // [mt][nt][reg]
    {
        float hv4[4];
        #pragma unroll
        for (int nt = 0; nt < 4; ++nt)
            hv4[nt] = hwh[(size_t)b * ND + o0 + nt * 16 + c15];
        #pragma unroll
        for (int mt = 0; mt < 2; ++mt)
            #pragma unroll
            for (int reg = 0; reg < 4; ++reg) {
                int r = mt * 16 + g * 4 + reg;
                size_t rowb = ((size_t)(b * NF + f0 + r)) * ND;
                #pragma unroll
                for (int nt = 0; nt < 4; ++nt) {
                    int col = o0 + nt * 16 + c15;
                    float bs = bsum[rowb + col];
                    bsv[mt][nt][reg] = bs;
                    float tv = tanhf(hv4[nt] + bs);
                    int byte = (r * 512 + col * 2) ^ ((r & 7) << 4);
                    *(short*)(tb + byte) = f2bf(tv);
                }
            }
    }
    __syncthreads();

    // ---- phase 2: e = tin @ w_e^T via MFMA ----
    f32x4 acc[2][4];
    #pragma unroll
    for (int mt = 0; mt < 2; ++mt)
        #pragma unroll
        for (int nt = 0; nt < 4; ++nt)
            acc[mt][nt] = (f32x4)0.f;
    #pragma unroll
    for (int ks = 0; ks < 8; ++ks) {
        int kb = ks * 32 + kgrp;
        bf16x8 afr[2];
        #pragma unroll
        for (int mt = 0; mt < 2; ++mt) {
            int row = mt * 16 + c15;
            int byte = (row * 512 + kb * 2) ^ ((row & 7) << 4);
            afr[mt] = *(const bf16x8*)(tb + byte);
        }
        #pragma unroll
        for (int nt = 0; nt < 4; ++nt) {
            int o = o0 + nt * 16 + c15;
            bf16x8 bfr = *(const bf16x8*)(w_e_bf + (size_t)o * ND + kb);
            #pragma unroll
            for (int mt = 0; mt < 2; ++mt)
                acc[mt][nt] = __builtin_amdgcn_mfma_f32_16x16x32_bf16(afr[mt], bfr, acc[mt][nt], 0, 0, 0);
        }
    }

    // ---- phase 3: softmax over cols, in-register (no max-subtract: |e| <= ~4) ----
    float ps[2][4];
    #pragma unroll
    for (int mt = 0; mt < 2; ++mt)
        #pragma unroll
        for (int reg = 0; reg < 4; ++reg) ps[mt][reg] = 0.f;
    #pragma unroll
    for (int mt = 0; mt < 2; ++mt)
        #pragma unroll
        for (int nt = 0; nt < 4; ++nt)
            #pragma unroll
            for (int reg = 0; reg < 4; ++reg) {
                float a = __expf(acc[mt][nt][reg]);
                acc[mt][nt][reg] = a;
                ps[mt][reg] += a;
            }
    // reduce over cols: lanes sharing a row differ in low 4 bits
    #pragma unroll
    for (int off = 1; off <= 8; off <<= 1)
        #pragma unroll
        for (int mt = 0; mt < 2; ++mt)
            #pragma unroll
            for (int reg = 0; reg < 4; ++reg)
                ps[mt][reg] += __shfl_xor(ps[mt][reg], off);
    if (c15 == 0) {
        #pragma unroll
        for (int mt = 0; mt < 2; ++mt)
            #pragma unroll
            for (int reg = 0; reg < 4; ++reg)
                sred[mt * 16 + g * 4 + reg][wv] = ps[mt][reg];
    }
    __syncthreads();
    float inv[2][4];
    #pragma unroll
    for (int mt = 0; mt < 2; ++mt)
        #pragma unroll
        for (int reg = 0; reg < 4; ++reg) {
            int r = mt * 16 + g * 4 + reg;
            inv[mt][reg] = 1.0f / (sred[r][0] + sred[r][1] + sred[r][2] + sred[r][3]);
        }
    #pragma unroll
    for (int mt = 0; mt < 2; ++mt)
        #pragma unroll
        for (int nt = 0; nt < 4; ++nt)
            #pragma unroll
            for (int reg = 0; reg < 4; ++reg)
                acc[mt][nt][reg] *= inv[mt][reg];   // acc = alpha (fp32)

    // ---- phase 4: c/cp partials, in-register (reduce over rows = lane bits 4-5) ----
    {
        float pc[4], pcp[4];
        #pragma unroll
        for (int nt = 0; nt < 4; ++nt) { pc[nt] = 0.f; pcp[nt] = 0.f; }
        #pragma unroll
        for (int mt = 0; mt < 2; ++mt)
            #pragma unroll
            for (int reg = 0; reg < 4; ++reg) {
                int r = mt * 16 + g * 4 + reg;
                size_t rowb = ((size_t)(b * NF + f0 + r)) * ND;
                size_t qrowb = (size_t)(f0 + r) * ND;
                #pragma unroll
                for (int nt = 0; nt < 4; ++nt) {
                    int col = o0 + nt * 16 + c15;
                    float a = acc[mt][nt][reg];
                    float fv = fin[rowb + col];
                    float qv = q[qrowb + col];
                    pc[nt] += a * fv;
                    pcp[nt] += a * (fv + qv);
                }
            }
        #pragma unroll
        for (int off = 16; off <= 32; off <<= 1)
            #pragma unroll
            for (int nt = 0; nt < 4; ++nt) {
                pc[nt]  += __shfl_xor(pc[nt], off);
                pcp[nt] += __shfl_xor(pcp[nt], off);
            }
        if (g == 0) {
            #pragma unroll
            for (int nt = 0; nt < 4; ++nt) {
                int col = o0 + nt * 16 + c15;
                cpart [((size_t)tile * NB + b) * ND + col] = pc[nt];
                cppart[((size_t)tile * NB + b) * ND + col] = pcp[nt];
            }
        }
    }

    // ---- alpha -> bf16 swizzled LDS (overwrite tin; all waves past phase-2 reads) ----
    #pragma unroll
    for (int mt = 0; mt < 2; ++mt)
        #pragma unroll
        for (int reg = 0; reg < 4; ++reg) {
            int r = mt * 16 + g * 4 + reg;
            #pragma unroll
            for (int nt = 0; nt < 4; ++nt) {
                int col = o0 + nt * 16 + c15;
                int byte = (r * 512 + col * 2) ^ ((r & 7) << 4);
                *(short*)(tb + byte) = f2bf(acc[mt][nt][reg]);
            }
        }
    __syncthreads();

    // ---- phase 5: bsum = bsv + alpha @ w_s^T via MFMA (pure store) ----
    {
        f32x4 acc2[2][4];
        #pragma unroll
        for (int mt = 0; mt < 2; ++mt)
            #pragma unroll
            for (int nt = 0; nt < 4; ++nt)
                acc2[mt][nt] = (f32x4)0.f;
        #pragma unroll
        for (int ks = 0; ks < 8; ++ks) {
            int kb = ks * 32 + kgrp;
            bf16x8 afr[2];
            #pragma unroll
            for (int mt = 0; mt < 2; ++mt) {
                int row = mt * 16 + c15;
                int byte = (row * 512 + kb * 2) ^ ((row & 7) << 4);
                afr[mt] = *(const bf16x8*)(tb + byte);
            }
            #pragma unroll
            for (int nt = 0; nt < 4; ++nt) {
                int o = o0 + nt * 16 + c15;
                bf16x8 bfr = *(const bf16x8*)(w_s_bf + (size_t)o * ND + kb);
                #pragma unroll
                for (int mt = 0; mt < 2; ++mt)
                    acc2[mt][nt] = __builtin_amdgcn_mfma_f32_16x16x32_bf16(afr[mt], bfr, acc2[mt][nt], 0, 0, 0);
            }
        }
        #pragma unroll
        for (int mt = 0; mt < 2; ++mt)
            #pragma unroll
            for (int reg = 0; reg < 4; ++reg) {
                int r = mt * 16 + g * 4 + reg;
                size_t rowb = ((size_t)(b * NF + f0 + r)) * ND;
                #pragma unroll
                for (int nt = 0; nt < 4; ++nt) {
                    int col = o0 + nt * 16 + c15;
                    bsum[rowb + col] = bsv[mt][nt][reg] + acc2[mt][nt][reg];
                }
            }
    }
}

extern "C" void kernel_launch(void* const* d_in, const int* in_sizes, int n_in,
                              void* d_out, int out_size, void* d_ws, size_t ws_size,
                              hipStream_t stream) {
    const float* fin  = (const float*)d_in[0];
    const int*   ids  = (const int*)  d_in[1];
    const float* emb  = (const float*)d_in[2];
    const float* w_e  = (const float*)d_in[3];
    const float* w_h  = (const float*)d_in[4];
    const float* w_f  = (const float*)d_in[5];
    const float* w_q  = (const float*)d_in[6];
    const float* w_s  = (const float*)d_in[7];
    const float* w_g  = (const float*)d_in[8];
    const float* w_ih = (const float*)d_in[9];
    const float* w_hh = (const float*)d_in[10];
    float* out = (float*)d_out;
    float* ws  = (float*)d_ws;

    size_t off = 0;
    float* q      = ws + off; off += (size_t)NF * ND;        // 131072
    float* scratch= ws + off; off += (size_t)NF * ND;        // qwq (init), then gatesT
    float* dec    = ws + off; off += (size_t)NB * NT * ND;   // 262144
    float* bsum   = ws + off; off += (size_t)NB * NF * ND;   // 4194304 (base + s@w_s^T)
    float* h      = ws + off; off += (size_t)NB * ND;
    float* cell   = ws + off; off += (size_t)NB * ND;
    float* hwh    = ws + off; off += (size_t)NB * ND;
    float* cpart  = ws + off; off += (size_t)NTILE * NB * ND;
    float* cppart = ws + off; off += (size_t)NTILE * NB * ND;
    short* w_e_bf = (short*)(ws + off); off += (size_t)ND * ND / 2;
    short* w_s_bf = (short*)(ws + off); off += (size_t)ND * ND / 2;

    float* qwq    = scratch;
    float* gatesT = scratch + 65536;

    hipMemsetAsync(h, 0, sizeof(float) * NB * ND, stream);
    hipMemsetAsync(cell, 0, sizeof(float) * NB * ND, stream);

    pe_kernel<<<NF, ND, 0, stream>>>(q);
    gather_kernel<<<NB * NT, ND, 0, stream>>>(ids, emb, dec);
    wcvt_kernel<<<ND * ND / 256, 256, 0, stream>>>(w_e, w_e_bf, ND * ND);
    wcvt_kernel<<<ND * ND / 256, 256, 0, stream>>>(w_s, w_s_bf, ND * ND);
    qwq_kernel<<<NF, ND, 0, stream>>>(q, w_q, qwq);
    base_kernel<<<NB * NTILE, ND, 0, stream>>>(fin, w_f, qwq, bsum);

    const size_t gates_lds = (size_t)(8 * 768 + NB * ZSTRIDE) * sizeof(float);  // 123008 B

    for (int t = 0; t < NT; ++t) {
        int mode = (t > 0) ? 3 : 1;
        gates_kernel<<<160, ND, gates_lds, stream>>>(t, mode, dec, cpart, cppart, h,
                                                     w_ih, w_hh, w_g, gatesT, out);
        cell_hwh_kernel<<<NB, ND, 0, stream>>>(gatesT, h, cell, w_h, hwh);
        attn_step_kernel<<<NB * NTILE, ND, 0, stream>>>(bsum, fin, q, hwh,
                                                        w_e_bf, w_s_bf, cpart, cppart);
    }
    // final pred for t = NT-1
    gates_kernel<<<160, ND, gates_lds, stream>>>(NT, 2, dec, cpart, cppart, h,
                                                 w_ih, w_hh, w_g, gatesT, out);
}

// Round 9
// 2675.717 us; speedup vs baseline: 4.8894x; 1.1398x over previous
//
#include <hip/hip_runtime.h>
#include <math.h>

#define NB 32      // batch
#define NF 512     // feature_size (source positions)
#define ND 256     // d_model
#define NT 32      // decode steps
#define RPB 32     // rows (f positions) per attention block
#define NTILE (NF / RPB)   // 16 f-tiles

typedef __attribute__((ext_vector_type(8))) short bf16x8;
typedef __attribute__((ext_vector_type(4))) float f32x4;

__device__ __forceinline__ float sigmoidf_(float x) { return 1.0f / (1.0f + __expf(-x)); }

__device__ __forceinline__ short f2bf(float x) {
    union { float f; unsigned u; } v; v.f = x;
    unsigned r = (v.u + 0x7FFF + ((v.u >> 16) & 1)) >> 16;
    return (short)r;
}

// ---------------- positional encoding q[F][D] ----------------
__global__ void pe_kernel(float* __restrict__ q) {
    int p = blockIdx.x;
    int d = threadIdx.x;
    float i2 = (float)((d >> 1) << 1);
    float rate = expf(-9.210340371976184f * (i2 / (float)ND));
    float ang = (float)p * rate;
    q[p * ND + d] = (d & 1) ? cosf(ang) : sinf(ang);
}

// ---------------- dec = emb[ids]  [B*T][D] ----------------
__global__ void gather_kernel(const int* __restrict__ ids, const float* __restrict__ emb,
                              float* __restrict__ dec) {
    int bt = blockIdx.x;
    int d = threadIdx.x;
    dec[(size_t)bt * ND + d] = emb[(size_t)ids[bt] * ND + d];
}

// ---------------- fp32 -> bf16 weight convert ----------------
__global__ void wcvt_kernel(const float* __restrict__ w, short* __restrict__ wb, int n) {
    int i = blockIdx.x * 256 + threadIdx.x;
    if (i < n) wb[i] = f2bf(w[i]);
}

// ---------------- qwq[p][o] = dot(q[p,:], w_q[o,:]) ----------------
__global__ void qwq_kernel(const float* __restrict__ q, const float* __restrict__ w_q,
                           float* __restrict__ qwq) {
    int p = blockIdx.x;
    int o = threadIdx.x;
    __shared__ float qs[ND];
    qs[o] = q[(size_t)p * ND + o];
    __syncthreads();
    const float4* wr = (const float4*)(w_q + (size_t)o * ND);
    float acc = 0.f;
    for (int k4 = 0; k4 < ND / 4; ++k4) {
        float4 w = wr[k4];
        int k = 4 * k4;
        acc += qs[k] * w.x + qs[k + 1] * w.y + qs[k + 2] * w.z + qs[k + 3] * w.w;
    }
    qwq[(size_t)p * ND + o] = acc;
}

// ---------------- bsum[b,f,o] = dot(f[b,f,:], w_f[o,:]) + qwq[f,o] ----------------
__global__ void base_kernel(const float* __restrict__ fin, const float* __restrict__ w_f,
                            const float* __restrict__ qwq, float* __restrict__ bsum) {
    int b = blockIdx.x / NTILE;
    int f0 = (blockIdx.x % NTILE) * RPB;
    int o = threadIdx.x;
    __shared__ float fs[RPB][ND];
    #pragma unroll
    for (int r = 0; r < RPB; ++r)
        fs[r][o] = fin[((size_t)(b * NF + f0 + r)) * ND + o];
    __syncthreads();
    float acc[RPB];
    #pragma unroll
    for (int r = 0; r < RPB; ++r) acc[r] = 0.f;
    const float4* wr = (const float4*)(w_f + (size_t)o * ND);
    for (int k4 = 0; k4 < ND / 4; ++k4) {
        float4 w = wr[k4];
        int k = 4 * k4;
        #pragma unroll
        for (int r = 0; r < RPB; ++r)
            acc[r] += fs[r][k] * w.x + fs[r][k + 1] * w.y + fs[r][k + 2] * w.z + fs[r][k + 3] * w.w;
    }
    #pragma unroll
    for (int r = 0; r < RPB; ++r)
        bsum[((size_t)(b * NF + f0 + r)) * ND + o] = acc[r] + qwq[(size_t)(f0 + r) * ND + o];
}

// ---------------- gates + pred, with inline Z/ZP construction ----------------
// gatesT layout: [b][j]  (j = gate*256 + o), coalesced for attn's per-b reads.
#define ZSTRIDE 769
#define ZPSTRIDE 513
__global__ void gates_kernel(int t, int mode,
                             const float* __restrict__ dec,
                             const float* __restrict__ cpart, const float* __restrict__ cppart,
                             const float* __restrict__ h,
                             const float* __restrict__ w_ih, const float* __restrict__ w_hh,
                             const float* __restrict__ w_g,
                             float* __restrict__ gatesT, float* __restrict__ out) {
    extern __shared__ float lds[];
    int bid = blockIdx.x;
    int tid = threadIdx.x;

    if (bid < 128) {
        if (!(mode & 1)) return;
        int j0 = bid * 8;
        float* wl = lds;              // [8][768]
        float* zl = lds + 8 * 768;    // [32][ZSTRIDE]
        float4* wl4 = (float4*)wl;
        for (int cc = 0; cc < 6; ++cc) {
            int idx4 = tid + cc * 256;
            int flat = idx4 * 4;
            int r = flat / 768;
            int col = flat - r * 768;
            float4 v;
            if (col < 512) v = *(const float4*)(w_ih + (size_t)(j0 + r) * 512 + col);
            else           v = *(const float4*)(w_hh + (size_t)(j0 + r) * 256 + (col - 512));
            wl4[idx4] = v;
        }
        // inline prep: Z[b] = [x_t | cpsum | h]
        for (int b = 0; b < NB; ++b) {
            int d = tid;
            float xv = (t < NT) ? dec[((size_t)b * NT + t) * ND + d] : 0.f;
            float cpsum = 0.f;
            if (t > 0) {
                #pragma unroll
                for (int tl = 0; tl < NTILE; ++tl)
                    cpsum += cppart[((size_t)tl * NB + b) * ND + d];
            }
            float hv = h[(size_t)b * ND + d];
            zl[b * ZSTRIDE + d]       = xv;
            zl[b * ZSTRIDE + 256 + d] = cpsum;
            zl[b * ZSTRIDE + 512 + d] = hv;
        }
        __syncthreads();
        int r = tid >> 5;
        int b = tid & 31;
        const float4* wr4 = (const float4*)(wl + r * 768);
        const float* zb = zl + b * ZSTRIDE;
        float acc = 0.f;
        #pragma unroll 8
        for (int k4 = 0; k4 < 192; ++k4) {
            float4 w = wr4[k4];
            int k = 4 * k4;
            acc += w.x * zb[k] + w.y * zb[k + 1] + w.z * zb[k + 2] + w.w * zb[k + 3];
        }
        gatesT[(size_t)b * 1024 + (j0 + r)] = acc;
    } else {
        if (!(mode & 2)) return;
        int p0 = (bid - 128) * 8;
        float* wl = lds;              // [8][512]
        float* zl = lds + 8 * 512;    // [32][ZPSTRIDE]
        float4* wl4 = (float4*)wl;
        for (int cc = 0; cc < 4; ++cc) {
            int idx4 = tid + cc * 256;
            int flat = idx4 * 4;
            int r = flat >> 9;
            int col = flat & 511;
            wl4[idx4] = *(const float4*)(w_g + (size_t)(p0 + r) * 512 + col);
        }
        // inline prep: ZP[b] = [csum | h]
        for (int b = 0; b < NB; ++b) {
            float csum = 0.f;
            #pragma unroll
            for (int tl = 0; tl < NTILE; ++tl)
                csum += cpart[((size_t)tl * NB + b) * ND + tid];
            zl[b * ZPSTRIDE + tid]       = csum;
            zl[b * ZPSTRIDE + 256 + tid] = h[(size_t)b * ND + tid];
        }
        __syncthreads();
        int r = tid >> 5;
        int b = tid & 31;
        const float4* wr4 = (const float4*)(wl + r * 512);
        const float* zb = zl + b * ZPSTRIDE;
        float acc = 0.f;
        #pragma unroll 8
        for (int k4 = 0; k4 < 128; ++k4) {
            float4 w = wr4[k4];
            int k = 4 * k4;
            acc += w.x * zb[k] + w.y * zb[k + 1] + w.z * zb[k + 2] + w.w * zb[k + 3];
        }
        out[((size_t)b * NT + (t - 1)) * ND + p0 + r] = acc;
    }
}

// ---------------- fused attention step: LSTM-pointwise + hwh + MFMA attn ----------------
// All global accesses coalesced (thread tid = column). C-layout <-> column-layout
// bridged via padded LDS transpose buffer xfer[32][257].
// C-fragment mapping: row = mt*16 + (l>>4)*4 + reg ; col = wv*64 + nt*16 + (l&15).
// tin_bf swizzle: element (r,k) at byte (r*512 + k*2) ^ ((r&7)<<4).
__global__ void __launch_bounds__(256) attn_step_kernel(
        float* __restrict__ bsum,
        const float* __restrict__ fin, const float* __restrict__ q,
        const float* __restrict__ gatesT,
        const float* __restrict__ cell_prev, float* __restrict__ cell_next,
        float* __restrict__ h_next,
        const float* __restrict__ w_h,
        const short* __restrict__ w_e_bf, const short* __restrict__ w_s_bf,
        float* __restrict__ cpart, float* __restrict__ cppart) {
    int b = blockIdx.x / NTILE;
    int tile = blockIdx.x % NTILE;
    int f0 = tile * RPB;
    int tid = threadIdx.x;
    int l = tid & 63;
    int wv = tid >> 6;

    __shared__ __align__(16) short tin_bf[RPB * ND];   // 16 KB, swizzled
    __shared__ float xfer[RPB * 257];                  // 32.9 KB transpose buffer
    __shared__ float hn[ND];
    __shared__ float sred[RPB][5];

    int o0 = wv * 64;
    int c15 = l & 15;
    int g = l >> 4;
    char* tb = (char*)tin_bf;

    // ---- phase 0: LSTM pointwise (redundant per tile) + hwh GEMV ----
    {
        float gi = gatesT[(size_t)b * 1024 + tid];
        float gf = gatesT[(size_t)b * 1024 + 256 + tid];
        float gg = gatesT[(size_t)b * 1024 + 512 + tid];
        float go = gatesT[(size_t)b * 1024 + 768 + tid];
        float cold = cell_prev[(size_t)b * ND + tid];
        float cnew = sigmoidf_(gf) * cold + sigmoidf_(gi) * tanhf(gg);
        float hval = sigmoidf_(go) * tanhf(cnew);
        if (tile == 0) {
            cell_next[(size_t)b * ND + tid] = cnew;
            h_next[(size_t)b * ND + tid] = hval;
        }
        hn[tid] = hval;
    }
    __syncthreads();
    float hwh_reg = 0.f;
    {
        const float4* whr = (const float4*)(w_h + (size_t)tid * ND);
        #pragma unroll 8
        for (int k4 = 0; k4 < ND / 4; ++k4) {
            float4 w = whr[k4]; int k = 4 * k4;
            hwh_reg += hn[k] * w.x + hn[k + 1] * w.y + hn[k + 2] * w.z + hn[k + 3] * w.w;
        }
    }

    // ---- phase 1: bsv (regs, row-indexed), tin = tanh(hwh+bsum) -> bf16 swizzled; coalesced ----
    float bsv[RPB];
    #pragma unroll
    for (int r = 0; r < RPB; ++r) {
        float bs = bsum[((size_t)(b * NF + f0 + r)) * ND + tid];
        bsv[r] = bs;
        int byte = (r * 512 + tid * 2) ^ ((r & 7) << 4);
        *(short*)(tb + byte) = f2bf(tanhf(hwh_reg + bs));
    }
    __syncthreads();

    // ---- phase 2: e = tin @ w_e^T via MFMA ----
    f32x4 acc[2][4];
    #pragma unroll
    for (int mt = 0; mt < 2; ++mt)
        #pragma unroll
        for (int nt = 0; nt < 4; ++nt)
            acc[mt][nt] = (f32x4)0.f;
    #pragma unroll
    for (int ks = 0; ks < 8; ++ks) {
        int kb = ks * 32 + g * 8;
        bf16x8 afr[2];
        #pragma unroll
        for (int mt = 0; mt < 2; ++mt) {
            int row = mt * 16 + c15;
            int byte = (row * 512 + kb * 2) ^ ((row & 7) << 4);
            afr[mt] = *(const bf16x8*)(tb + byte);
        }
        #pragma unroll
        for (int nt = 0; nt < 4; ++nt) {
            int o = o0 + nt * 16 + c15;
            bf16x8 bfr = *(const bf16x8*)(w_e_bf + (size_t)o * ND + kb);
            #pragma unroll
            for (int mt = 0; mt < 2; ++mt)
                acc[mt][nt] = __builtin_amdgcn_mfma_f32_16x16x32_bf16(afr[mt], bfr, acc[mt][nt], 0, 0, 0);
        }
    }

    // ---- phase 3: softmax over cols, in-register (no max-subtract; |e| small) ----
    {
        float ps[2][4];
        #pragma unroll
        for (int mt = 0; mt < 2; ++mt)
            #pragma unroll
            for (int reg = 0; reg < 4; ++reg) ps[mt][reg] = 0.f;
        #pragma unroll
        for (int mt = 0; mt < 2; ++mt)
            #pragma unroll
            for (int nt = 0; nt < 4; ++nt)
                #pragma unroll
                for (int reg = 0; reg < 4; ++reg) {
                    float a = __expf(acc[mt][nt][reg]);
                    acc[mt][nt][reg] = a;
                    ps[mt][reg] += a;
                }
        #pragma unroll
        for (int off = 1; off <= 8; off <<= 1)
            #pragma unroll
            for (int mt = 0; mt < 2; ++mt)
                #pragma unroll
                for (int reg = 0; reg < 4; ++reg)
                    ps[mt][reg] += __shfl_xor(ps[mt][reg], off);
        if (c15 == 0) {
            #pragma unroll
            for (int mt = 0; mt < 2; ++mt)
                #pragma unroll
                for (int reg = 0; reg < 4; ++reg)
                    sred[mt * 16 + g * 4 + reg][wv] = ps[mt][reg];
        }
        __syncthreads();
        #pragma unroll
        for (int mt = 0; mt < 2; ++mt)
            #pragma unroll
            for (int reg = 0; reg < 4; ++reg) {
                int r = mt * 16 + g * 4 + reg;
                float inv = 1.0f / (sred[r][0] + sred[r][1] + sred[r][2] + sred[r][3]);
                #pragma unroll
                for (int nt = 0; nt < 4; ++nt)
                    acc[mt][nt][reg] *= inv;      // acc = alpha (fp32, C-layout)
            }
    }

    // ---- phase 4: alpha C-layout -> xfer[row][col] ----
    #pragma unroll
    for (int mt = 0; mt < 2; ++mt)
        #pragma unroll
        for (int reg = 0; reg < 4; ++reg) {
            int r = mt * 16 + g * 4 + reg;
            #pragma unroll
            for (int nt = 0; nt < 4; ++nt)
                xfer[r * 257 + o0 + nt * 16 + c15] = acc[mt][nt][reg];
        }
    __syncthreads();

    // ---- phase 5: c/cp partials col-parallel (coalesced fin/q); alpha -> bf16 tin ----
    {
        float pc = 0.f, pcp = 0.f;
        #pragma unroll
        for (int r = 0; r < RPB; ++r) {
            float a = xfer[r * 257 + tid];
            float fv = fin[((size_t)(b * NF + f0 + r)) * ND + tid];
            float qv = q[(size_t)(f0 + r) * ND + tid];
            pc += a * fv;
            pcp += a * (fv + qv);
            int byte = (r * 512 + tid * 2) ^ ((r & 7) << 4);
            *(short*)(tb + byte) = f2bf(a);
        }
        cpart [((size_t)tile * NB + b) * ND + tid] = pc;
        cppart[((size_t)tile * NB + b) * ND + tid] = pcp;
    }
    __syncthreads();

    // ---- phase 6: alpha @ w_s^T via MFMA -> xfer ----
    {
        f32x4 acc2[2][4];
        #pragma unroll
        for (int mt = 0; mt < 2; ++mt)
            #pragma unroll
            for (int nt = 0; nt < 4; ++nt)
                acc2[mt][nt] = (f32x4)0.f;
        #pragma unroll
        for (int ks = 0; ks < 8; ++ks) {
            int kb = ks * 32 + g * 8;
            bf16x8 afr[2];
            #pragma unroll
            for (int mt = 0; mt < 2; ++mt) {
                int row = mt * 16 + c15;
                int byte = (row * 512 + kb * 2) ^ ((row & 7) << 4);
                afr[mt] = *(const bf16x8*)(tb + byte);
            }
            #pragma unroll
            for (int nt = 0; nt < 4; ++nt) {
                int o = o0 + nt * 16 + c15;
                bf16x8 bfr = *(const bf16x8*)(w_s_bf + (size_t)o * ND + kb);
                #pragma unroll
                for (int mt = 0; mt < 2; ++mt)
                    acc2[mt][nt] = __builtin_amdgcn_mfma_f32_16x16x32_bf16(afr[mt], bfr, acc2[mt][nt], 0, 0, 0);
            }
        }
        #pragma unroll
        for (int mt = 0; mt < 2; ++mt)
            #pragma unroll
            for (int reg = 0; reg < 4; ++reg) {
                int r = mt * 16 + g * 4 + reg;
                #pragma unroll
                for (int nt = 0; nt < 4; ++nt)
                    xfer[r * 257 + o0 + nt * 16 + c15] = acc2[mt][nt][reg];
            }
    }
    __syncthreads();

    // ---- phase 7: bsum = bsv + xfer, coalesced store ----
    #pragma unroll
    for (int r = 0; r < RPB; ++r)
        bsum[((size_t)(b * NF + f0 + r)) * ND + tid] = bsv[r] + xfer[r * 257 + tid];
}

extern "C" void kernel_launch(void* const* d_in, const int* in_sizes, int n_in,
                              void* d_out, int out_size, void* d_ws, size_t ws_size,
                              hipStream_t stream) {
    const float* fin  = (const float*)d_in[0];
    const int*   ids  = (const int*)  d_in[1];
    const float* emb  = (const float*)d_in[2];
    const float* w_e  = (const float*)d_in[3];
    const float* w_h  = (const float*)d_in[4];
    const float* w_f  = (const float*)d_in[5];
    const float* w_q  = (const float*)d_in[6];
    const float* w_s  = (const float*)d_in[7];
    const float* w_g  = (const float*)d_in[8];
    const float* w_ih = (const float*)d_in[9];
    const float* w_hh = (const float*)d_in[10];
    float* out = (float*)d_out;
    float* ws  = (float*)d_ws;

    size_t off = 0;
    float* q      = ws + off; off += (size_t)NF * ND;        // 131072
    float* scratch= ws + off; off += (size_t)NF * ND;        // qwq (init), then gatesT
    float* dec    = ws + off; off += (size_t)NB * NT * ND;   // 262144
    float* bsum   = ws + off; off += (size_t)NB * NF * ND;   // 4194304 (base + s@w_s^T)
    float* h0     = ws + off; off += (size_t)NB * ND;
    float* h1     = ws + off; off += (size_t)NB * ND;
    float* cell0  = ws + off; off += (size_t)NB * ND;
    float* cell1  = ws + off; off += (size_t)NB * ND;
    float* cpart  = ws + off; off += (size_t)NTILE * NB * ND;
    float* cppart = ws + off; off += (size_t)NTILE * NB * ND;
    short* w_e_bf = (short*)(ws + off); off += (size_t)ND * ND / 2;
    short* w_s_bf = (short*)(ws + off); off += (size_t)ND * ND / 2;

    float* qwq    = scratch;
    float* gatesT = scratch;   // 32*1024 floats; reused after base_kernel consumed qwq

    float* hbuf[2]    = { h0, h1 };
    float* cellbuf[2] = { cell0, cell1 };

    hipMemsetAsync(h0, 0, sizeof(float) * NB * ND, stream);
    hipMemsetAsync(cell0, 0, sizeof(float) * NB * ND, stream);

    pe_kernel<<<NF, ND, 0, stream>>>(q);
    gather_kernel<<<NB * NT, ND, 0, stream>>>(ids, emb, dec);
    wcvt_kernel<<<ND * ND / 256, 256, 0, stream>>>(w_e, w_e_bf, ND * ND);
    wcvt_kernel<<<ND * ND / 256, 256, 0, stream>>>(w_s, w_s_bf, ND * ND);
    qwq_kernel<<<NF, ND, 0, stream>>>(q, w_q, qwq);
    base_kernel<<<NB * NTILE, ND, 0, stream>>>(fin, w_f, qwq, bsum);

    const size_t gates_lds = (size_t)(8 * 768 + NB * ZSTRIDE) * sizeof(float);  // 123008 B

    for (int t = 0; t < NT; ++t) {
        int mode = (t > 0) ? 3 : 1;
        int p = t & 1;
        gates_kernel<<<160, ND, gates_lds, stream>>>(t, mode, dec, cpart, cppart, hbuf[p],
                                                     w_ih, w_hh, w_g, gatesT, out);
        attn_step_kernel<<<NB * NTILE, ND, 0, stream>>>(bsum, fin, q, gatesT,
                                                        cellbuf[p], cellbuf[p ^ 1], hbuf[p ^ 1],
                                                        w_h, w_e_bf, w_s_bf, cpart, cppart);
    }
    // final pred for t = NT-1 (h after step NT-1 lives in hbuf[NT&1] = hbuf[0])
    gates_kernel<<<160, ND, gates_lds, stream>>>(NT, 2, dec, cpart, cppart, hbuf[0],
                                                 w_ih, w_hh, w_g, gatesT, out);
}